// Round 7
// baseline (534.110 us; speedup 1.0000x reference)
//
#include <hip/hip_runtime.h>
#include <hip/hip_bf16.h>

typedef __attribute__((ext_vector_type(8))) short bf16x8;
typedef __attribute__((ext_vector_type(4))) short s16x4;
typedef __attribute__((ext_vector_type(2))) int i32x2;
typedef __attribute__((ext_vector_type(4))) float f32x4;

__device__ __forceinline__ short f2bf(float f) {
  unsigned u = __builtin_bit_cast(unsigned, f);
  u = (u + 0x7FFFu + ((u >> 16) & 1u)) >> 16;
  return (short)u;
}

__device__ __forceinline__ void gload_lds16(const void* g, void* l) {
  __builtin_amdgcn_global_load_lds(
      (const __attribute__((address_space(1))) void*)g,
      (__attribute__((address_space(3))) void*)l, 16, 0, 0);
}

__device__ __forceinline__ f32x4 mfma16(s16x4 a, s16x4 b, f32x4 c) {
#if __has_builtin(__builtin_amdgcn_mfma_f32_16x16x16bf16_1k)
  return __builtin_amdgcn_mfma_f32_16x16x16bf16_1k(a, b, c, 0, 0, 0);
#else
  asm("v_mfma_f32_16x16x16_bf16 %0, %1, %2, %0" : "+v"(c) : "v"(a), "v"(b));
  return c;
#endif
}

#define SBAR()       asm volatile("s_barrier" ::: "memory")
#define WAIT_VM4()   asm volatile("s_waitcnt vmcnt(4)" ::: "memory")
#define WAIT_VM0()   asm volatile("s_waitcnt vmcnt(0)" ::: "memory")
#define WAIT_LGKM0() asm volatile("s_waitcnt lgkmcnt(0)" ::: "memory")

// ---------------------------------------------------------------- prep kernels

// x (B,240,512) fp32 -> xb (B*256,512) bf16, zero-padded rows 240..255
__global__ void k_convert_x(const float* __restrict__ x, short* __restrict__ xb) {
  int i = blockIdx.x * 256 + threadIdx.x;      // group of 4 elements
  int c4 = i & 127;
  int row = i >> 7;                            // 0..32767
  int b = row >> 8, t = row & 255;
  s16x4 o = {0, 0, 0, 0};
  if (t < 240) {
    const float4 v = *(const float4*)(x + (size_t)(b * 240 + t) * 512 + c4 * 4);
    o.x = f2bf(v.x); o.y = f2bf(v.y); o.z = f2bf(v.z); o.w = f2bf(v.w);
  }
  *(s16x4*)(xb + (size_t)row * 512 + c4 * 4) = o;
}

// W (K,N) fp32 -> Wt (N,K) bf16
__global__ void k_transpose_w(const float* __restrict__ W, short* __restrict__ Wt,
                              int K, int N) {
  int i = blockIdx.x * 256 + threadIdx.x;      // n*K + k
  if (i >= K * N) return;
  int k = i % K, n = i / K;
  Wt[i] = f2bf(W[(size_t)k * N + n]);
}

// rel_bias_table (961,16) -> expB in swapped-QK fragment layout:
// expB[((h*16+qtl)*15 + j)*64 + lane][r] = exp(bias(h, q=qtl*16+(lane&15),
//                                                   k=j*16+4*(lane>>4)+r))
__global__ void k_biasfrag(const float* __restrict__ table, float* __restrict__ expB) {
  int i = blockIdx.x * 256 + threadIdx.x;      // 245760 threads
  int lane = i & 63;
  int rest = i >> 6;
  int j = rest % 15;
  int hq = rest / 15;                          // h*16 + qtl
  int q = (hq & 15) * 16 + (lane & 15);
  int h = hq >> 4;
  int kbase = j * 16 + ((lane >> 4) << 2);
  float4 o;
  float* op = &o.x;
#pragma unroll
  for (int r = 0; r < 4; ++r) {
    int k = kbase + r;
    int idx = ((q >> 4) - (k >> 4) + 15) * 31 + ((q & 15) - (k & 15) + 15);
    op[r] = __builtin_amdgcn_exp2f(table[idx * 16 + h] * 1.4426950408889634f);
  }
  *(float4*)(expB + (size_t)i * 4) = o;
}

// ---------------------------------------------------------------- GEMM
// C = A(32768 x 512) * Bt(N x 512)^T + bias. BM=BN=256, 8 waves (2m x 4n of
// 128x64 wave tiles), BK=32, 2-deep counted-vmcnt pipeline (vmcnt(4), never
// drained in loop), frag-ordered LDS (0 conflicts), XCD-swizzled 1-D grid.
// MODE 0: QKV epilogue. Q,K scatter to (b,h,t,d); V packed 8B to (b,h,d,t).
//         Q pre-scaled by hd^-0.5*log2(e).
// MODE 1: proj epilogue (fp32, drop padded rows).
template <int MODE, int NBN>
__global__ __launch_bounds__(512, 2)
void k_gemm(const short* __restrict__ A, const short* __restrict__ Bt,
            const float* __restrict__ bias,
            short* __restrict__ qo, short* __restrict__ ko, short* __restrict__ vo,
            float* __restrict__ fo) {
  __shared__ alignas(16) short lds[2][32][512];  // [buf][16 A-blk + 16 B-blk][frag]
  const int lane = threadIdx.x & 63;
  const int w = threadIdx.x >> 6;   // 0..7
  const int wm = w >> 2;            // 0..1 (m offset 128)
  const int wn = w & 3;             // 0..3 (n offset 64)
  const int arow = lane & 15;
  const int g = lane >> 4;
  const int kc8 = g * 8;

  const int nwg = 128 * NBN;
  const int bid = blockIdx.x;
  const int swz = (bid & 7) * (nwg >> 3) + (bid >> 3);
  const int nb = swz % NBN, mc = swz / NBN;
  const int n0 = nb * 256, m0 = mc * 256;

  // wave w stages tiles 4w..4w+3 (tile<16: A m-blk16, else B n-blk16)
  const short* gsrc[4];
#pragma unroll
  for (int s = 0; s < 4; ++s) {
    const int t = w * 4 + s;
    gsrc[s] = (t < 16 ? A + (size_t)(m0 + t * 16 + arow) * 512
                      : Bt + (size_t)(n0 + (t - 16) * 16 + arow) * 512) + kc8;
  }

#define STAGE(buf, k0)                                       \
  {                                                          \
    _Pragma("unroll")                                        \
    for (int s = 0; s < 4; ++s)                              \
      gload_lds16(gsrc[s] + (k0), &lds[buf][w * 4 + s][0]);  \
  }

  float bv[4];
#pragma unroll
  for (int j = 0; j < 4; ++j) bv[j] = bias[n0 + wn * 64 + j * 16 + arow];

  f32x4 acc[8][4] = {};
  STAGE(0, 0);
  STAGE(1, 32);
#pragma unroll
  for (int kt = 0; kt < 16; ++kt) {
    const int cur = kt & 1;
    if (kt < 15) WAIT_VM4(); else WAIT_VM0();   // oldest stage (tile kt) landed
    SBAR();
    bf16x8 af[8], bfr[4];
#pragma unroll
    for (int i = 0; i < 8; ++i)
      af[i] = *(const bf16x8*)&lds[cur][wm * 8 + i][lane * 8];
#pragma unroll
    for (int j = 0; j < 4; ++j)
      bfr[j] = *(const bf16x8*)&lds[cur][16 + wn * 4 + j][lane * 8];
    WAIT_LGKM0();                               // my reads of buf[cur] done
    __builtin_amdgcn_sched_barrier(0);
    SBAR();                                     // all reads done -> reuse ok
    if (kt < 14) STAGE(cur, (kt + 2) * 32);     // prefetch 2 ahead
#pragma unroll
    for (int i = 0; i < 8; ++i)
#pragma unroll
      for (int j = 0; j < 4; ++j)
        acc[i][j] = __builtin_amdgcn_mfma_f32_16x16x32_bf16(af[i], bfr[j], acc[i][j], 0, 0, 0);
  }
#undef STAGE

  const float sc = 0.17677669529663687f * 1.4426950408889634f;
  if (MODE == 0) {
    const int part = n0 >> 9;                    // 0:Q 1:K 2:V (uniform per block)
    short* dst = part == 0 ? qo : (part == 1 ? ko : vo);
    const float osc = part == 0 ? sc : 1.f;
    if (part == 2) {
      // V: (b,h,d,t) -> lane's 4 consecutive t = one 8B store
#pragma unroll
      for (int i = 0; i < 8; ++i) {
        const int mm0 = m0 + wm * 128 + i * 16 + g * 4;
        const int bb = mm0 >> 8, tt0 = mm0 & 255;
#pragma unroll
        for (int j = 0; j < 4; ++j) {
          const int c = n0 + wn * 64 + j * 16 + arow;
          const int d = c & 31, hh = (c >> 5) & 15;
          s16x4 qv;
#pragma unroll
          for (int r = 0; r < 4; ++r)
            qv[r] = f2bf(acc[i][j][r] + bv[j]);
          *(s16x4*)(dst + ((size_t)(bb * 16 + hh) * 32 + d) * 256 + tt0) = qv;
        }
      }
    } else {
      // Q,K: (b,h,t,d) scatter
#pragma unroll
      for (int i = 0; i < 8; ++i) {
        const int mm0 = m0 + wm * 128 + i * 16 + g * 4;
        const int bb = mm0 >> 8, tt0 = mm0 & 255;
#pragma unroll
        for (int j = 0; j < 4; ++j) {
          const int c = n0 + wn * 64 + j * 16 + arow;
          const int d = c & 31, hh = (c >> 5) & 15;
#pragma unroll
          for (int r = 0; r < 4; ++r)
            dst[((size_t)(bb * 16 + hh) * 256 + tt0 + r) * 32 + d] =
                f2bf((acc[i][j][r] + bv[j]) * osc);
        }
      }
    }
  } else {
#pragma unroll
    for (int i = 0; i < 8; ++i) {
      const int mm0 = m0 + wm * 128 + i * 16 + g * 4;
      const int bb = mm0 >> 8, tt0 = mm0 & 255;
#pragma unroll
      for (int j = 0; j < 4; ++j) {
        const int c = n0 + wn * 64 + j * 16 + arow;
#pragma unroll
        for (int r = 0; r < 4; ++r) {
          const int tt = tt0 + r;
          if (tt < 240) fo[(size_t)(bb * 240 + tt) * 512 + c] = acc[i][j][r] + bv[j];
        }
      }
    }
  }
}

// ---------------------------------------------------------------- attention
// One WG (8 waves, 512 thr) per (b,h); each wave owns 2 q-tiles. Swapped QK^T:
// lane holds S[q=lane&15][k=j*16+4g+r] -> softmax row fully lane-local; P
// packs directly into the A-fragment of mfma_f32_16x16x16_bf16 for PV.
// 31.5KB LDS x 4 blocks/CU x 8 waves = 32 waves/CU (100% occupancy, 64 VGPR).
__global__ __launch_bounds__(512, 8)
void k_attn(const short* __restrict__ Qg, const short* __restrict__ Kg,
            const short* __restrict__ Vg, const float* __restrict__ expB,
            short* __restrict__ O) {
  __shared__ alignas(16) short ldsK[15 * 512];      // frag-ordered K tiles
  __shared__ alignas(16) short ldsVT[32 * 264];     // V^T [d][t], stride 264
  const int lane = threadIdx.x & 63;
  const int w = threadIdx.x >> 6;                   // 0..7
  const int bh = blockIdx.x;
  const int h = bh & 15, b = bh >> 4;
  const short* Qb = Qg + (size_t)bh * 8192;
  const short* Kb = Kg + (size_t)bh * 8192;
  const short* Vb = Vg + (size_t)bh * 8192;
  const int arow = lane & 15;
  const int g = lane >> 4;

#pragma unroll
  for (int kt = 0; kt < 15; ++kt)
    if ((kt & 7) == w)
      gload_lds16(Kb + (kt * 16 + arow) * 32 + g * 8, &ldsK[kt * 512]);

  // V is (d,t): build padded V^T in LDS with wide copies
#pragma unroll
  for (int p = 0; p < 2; ++p) {
    int idx = p * 512 + threadIdx.x;   // 0..1023
    int d = idx >> 5, tc = idx & 31;
    *(bf16x8*)&ldsVT[d * 264 + tc * 8] = *(const bf16x8*)(Vb + d * 256 + tc * 8);
  }

  // Q is (b,h,t,d): direct fragment loads
  bf16x8 qf[2];
#pragma unroll
  for (int i = 0; i < 2; ++i)
    qf[i] = *(const bf16x8*)(Qb + ((w * 2 + i) * 16 + arow) * 32 + g * 8);
  __syncthreads();

  const f32x4 zf = {0.f, 0.f, 0.f, 0.f};
#pragma unroll
  for (int qt = 0; qt < 2; ++qt) {
    // ---- QK^T (swapped operands) ----
    f32x4 sacc[15];
#pragma unroll
    for (int j = 0; j < 15; ++j) {
      bf16x8 kf = *(const bf16x8*)&ldsK[j * 512 + lane * 8];
      sacc[j] = __builtin_amdgcn_mfma_f32_16x16x32_bf16(kf, qf[qt], zf, 0, 0, 0);
    }
    // ---- row max ----
    float m = fmaxf(fmaxf(sacc[0][0], sacc[0][1]), fmaxf(sacc[0][2], sacc[0][3]));
#pragma unroll
    for (int j = 1; j < 15; ++j)
      m = fmaxf(m, fmaxf(fmaxf(sacc[j][0], sacc[j][1]), fmaxf(sacc[j][2], sacc[j][3])));
    m = fmaxf(m, __shfl_xor(m, 16));
    m = fmaxf(m, __shfl_xor(m, 32));
    // ---- p = exp2(S - m) * exp(bias), pack to bf16 A-frags ----
    const float* ebp = expB + (size_t)((h * 16 + w * 2 + qt) * 15) * 256 + lane * 4;
    float sum = 0.f;
    s16x4 pa[15];
#pragma unroll
    for (int j = 0; j < 15; ++j) {
      float4 eb = *(const float4*)(ebp + j * 256);
      float p0 = __builtin_amdgcn_exp2f(sacc[j][0] - m) * eb.x;
      float p1 = __builtin_amdgcn_exp2f(sacc[j][1] - m) * eb.y;
      float p2 = __builtin_amdgcn_exp2f(sacc[j][2] - m) * eb.z;
      float p3 = __builtin_amdgcn_exp2f(sacc[j][3] - m) * eb.w;
      sum += (p0 + p1) + (p2 + p3);
      i32x2 pk;
      asm("v_cvt_pk_bf16_f32 %0, %1, %2" : "=v"(pk.x) : "v"(p0), "v"(p1));
      asm("v_cvt_pk_bf16_f32 %0, %1, %2" : "=v"(pk.y) : "v"(p2), "v"(p3));
      pa[j] = __builtin_bit_cast(s16x4, pk);
    }
    sum += __shfl_xor(sum, 16);
    sum += __shfl_xor(sum, 32);
    float rs = __builtin_amdgcn_rcpf(sum);
    float rsr[4];
#pragma unroll
    for (int r = 0; r < 4; ++r)
      rsr[r] = __shfl(rs, (lane & 48) + ((lane & 48) >> 2) + r, 64);
    // ---- PV: P A-frags x V^T B-frags, K=16 ----
    f32x4 oacc[2] = {};
#pragma unroll
    for (int j = 0; j < 15; ++j) {
#pragma unroll
      for (int dt = 0; dt < 2; ++dt) {
        s16x4 vt = *(const s16x4*)&ldsVT[(dt * 16 + arow) * 264 + j * 16 + g * 4];
        oacc[dt] = mfma16(pa[j], vt, oacc[dt]);
      }
    }
    const int q0 = (w * 2 + qt) * 16;
#pragma unroll
    for (int dt = 0; dt < 2; ++dt)
#pragma unroll
      for (int r = 0; r < 4; ++r)
        O[(size_t)(b * 256 + q0 + 4 * g + r) * 512 + h * 32 + dt * 16 + arow] =
            f2bf(oacc[dt][r] * rsr[r]);
  }
}

// ---------------------------------------------------------------- launch

extern "C" void kernel_launch(void* const* d_in, const int* in_sizes, int n_in,
                              void* d_out, int out_size, void* d_ws, size_t ws_size,
                              hipStream_t stream) {
  const float* x      = (const float*)d_in[0];
  const float* qkv_w  = (const float*)d_in[1];
  const float* qkv_b  = (const float*)d_in[2];
  const float* proj_w = (const float*)d_in[3];
  const float* proj_b = (const float*)d_in[4];
  const float* table  = (const float*)d_in[5];
  float* out = (float*)d_out;

  char* ws = (char*)d_ws;
  short* xb      = (short*)(ws);                 // 33,554,432 B (reused as attn_out)
  short* Qg      = (short*)(ws + 33554432u);     // 33,554,432 B  (b,h,t,d)
  short* Kg      = (short*)(ws + 67108864u);     // 33,554,432 B  (b,h,t,d)
  short* Vg      = (short*)(ws + 100663296u);    // 33,554,432 B  (b,h,d,t)
  float* expBf   = (float*)(ws + 134217728u);    //  3,932,160 B
  short* qkv_wt  = (short*)(ws + 138412032u);    //  1,572,864 B
  short* proj_wt = (short*)(ws + 139984896u);    //    524,288 B

  k_convert_x<<<16384, 256, 0, stream>>>(x, xb);
  k_transpose_w<<<(1536 * 512) / 256, 256, 0, stream>>>(qkv_w, qkv_wt, 512, 1536);
  k_transpose_w<<<(512 * 512) / 256, 256, 0, stream>>>(proj_w, proj_wt, 512, 512);
  k_biasfrag<<<960, 256, 0, stream>>>(table, expBf);
  k_gemm<0, 6><<<768, 512, 0, stream>>>(xb, qkv_wt, qkv_b, Qg, Kg, Vg, nullptr);
  k_attn<<<2048, 512, 0, stream>>>(Qg, Kg, Vg, expBf, xb);
  k_gemm<1, 2><<<256, 512, 0, stream>>>(xb, proj_wt, proj_b, nullptr, nullptr, nullptr, out);
}

// Round 8
// 209.127 us; speedup vs baseline: 2.5540x; 2.5540x over previous
//
#include <hip/hip_runtime.h>
#include <hip/hip_bf16.h>

typedef __attribute__((ext_vector_type(8))) short bf16x8;
typedef __attribute__((ext_vector_type(4))) short s16x4;
typedef __attribute__((ext_vector_type(2))) int i32x2;
typedef __attribute__((ext_vector_type(4))) float f32x4;

__device__ __forceinline__ short f2bf(float f) {
  unsigned u = __builtin_bit_cast(unsigned, f);
  u = (u + 0x7FFFu + ((u >> 16) & 1u)) >> 16;
  return (short)u;
}

__device__ __forceinline__ void gload_lds16(const void* g, void* l) {
  __builtin_amdgcn_global_load_lds(
      (const __attribute__((address_space(1))) void*)g,
      (__attribute__((address_space(3))) void*)l, 16, 0, 0);
}

__device__ __forceinline__ f32x4 mfma16(s16x4 a, s16x4 b, f32x4 c) {
#if __has_builtin(__builtin_amdgcn_mfma_f32_16x16x16bf16_1k)
  return __builtin_amdgcn_mfma_f32_16x16x16bf16_1k(a, b, c, 0, 0, 0);
#else
  asm("v_mfma_f32_16x16x16_bf16 %0, %1, %2, %0" : "+v"(c) : "v"(a), "v"(b));
  return c;
#endif
}

#define SBAR()       asm volatile("s_barrier" ::: "memory")
#define WAIT_VM4()   asm volatile("s_waitcnt vmcnt(4)" ::: "memory")
#define WAIT_VM0()   asm volatile("s_waitcnt vmcnt(0)" ::: "memory")
#define WAIT_LGKM0() asm volatile("s_waitcnt lgkmcnt(0)" ::: "memory")

// ---------------------------------------------------------------- prep kernels

// x (B,240,512) fp32 -> xb (B*256,512) bf16, zero-padded rows 240..255
__global__ void k_convert_x(const float* __restrict__ x, short* __restrict__ xb) {
  int i = blockIdx.x * 256 + threadIdx.x;      // group of 4 elements
  int c4 = i & 127;
  int row = i >> 7;                            // 0..32767
  int b = row >> 8, t = row & 255;
  s16x4 o = {0, 0, 0, 0};
  if (t < 240) {
    const float4 v = *(const float4*)(x + (size_t)(b * 240 + t) * 512 + c4 * 4);
    o.x = f2bf(v.x); o.y = f2bf(v.y); o.z = f2bf(v.z); o.w = f2bf(v.w);
  }
  *(s16x4*)(xb + (size_t)row * 512 + c4 * 4) = o;
}

// W (K,N) fp32 -> Wt (N,K) bf16
__global__ void k_transpose_w(const float* __restrict__ W, short* __restrict__ Wt,
                              int K, int N) {
  int i = blockIdx.x * 256 + threadIdx.x;      // n*K + k
  if (i >= K * N) return;
  int k = i % K, n = i / K;
  Wt[i] = f2bf(W[(size_t)k * N + n]);
}

// rel_bias_table (961,16) -> expB in swapped-QK fragment layout:
// expB[((h*16+qtl)*15 + j)*64 + lane][r] = exp(bias(h, q=qtl*16+(lane&15),
//                                                   k=j*16+4*(lane>>4)+r))
__global__ void k_biasfrag(const float* __restrict__ table, float* __restrict__ expB) {
  int i = blockIdx.x * 256 + threadIdx.x;      // 245760 threads
  int lane = i & 63;
  int rest = i >> 6;
  int j = rest % 15;
  int hq = rest / 15;                          // h*16 + qtl
  int q = (hq & 15) * 16 + (lane & 15);
  int h = hq >> 4;
  int kbase = j * 16 + ((lane >> 4) << 2);
  float4 o;
  float* op = &o.x;
#pragma unroll
  for (int r = 0; r < 4; ++r) {
    int k = kbase + r;
    int idx = ((q >> 4) - (k >> 4) + 15) * 31 + ((q & 15) - (k & 15) + 15);
    op[r] = __builtin_amdgcn_exp2f(table[idx * 16 + h] * 1.4426950408889634f);
  }
  *(float4*)(expB + (size_t)i * 4) = o;
}

// ---------------------------------------------------------------- GEMM
// C = A(32768 x 512) * Bt(N x 512)^T + bias. BM=BN=256, 8 waves (2m x 4n of
// 128x64 wave tiles), BK=32, 2-deep counted-vmcnt pipeline (vmcnt(4), never
// drained in loop), frag-ordered LDS (0 conflicts), XCD-swizzled 1-D grid.
// MODE 0: QKV epilogue. Q,K scatter to (b,h,t,d); V packed 8B to (b,h,d,t).
//         Q pre-scaled by hd^-0.5*log2(e).
// MODE 1: proj epilogue (fp32, drop padded rows).
template <int MODE, int NBN>
__global__ __launch_bounds__(512, 2)
void k_gemm(const short* __restrict__ A, const short* __restrict__ Bt,
            const float* __restrict__ bias,
            short* __restrict__ qo, short* __restrict__ ko, short* __restrict__ vo,
            float* __restrict__ fo) {
  __shared__ alignas(16) short lds[2][32][512];  // [buf][16 A-blk + 16 B-blk][frag]
  const int lane = threadIdx.x & 63;
  const int w = threadIdx.x >> 6;   // 0..7
  const int wm = w >> 2;            // 0..1 (m offset 128)
  const int wn = w & 3;             // 0..3 (n offset 64)
  const int arow = lane & 15;
  const int g = lane >> 4;
  const int kc8 = g * 8;

  const int nwg = 128 * NBN;
  const int bid = blockIdx.x;
  const int swz = (bid & 7) * (nwg >> 3) + (bid >> 3);
  const int nb = swz % NBN, mc = swz / NBN;
  const int n0 = nb * 256, m0 = mc * 256;

  // wave w stages tiles 4w..4w+3 (tile<16: A m-blk16, else B n-blk16)
  const short* gsrc[4];
#pragma unroll
  for (int s = 0; s < 4; ++s) {
    const int t = w * 4 + s;
    gsrc[s] = (t < 16 ? A + (size_t)(m0 + t * 16 + arow) * 512
                      : Bt + (size_t)(n0 + (t - 16) * 16 + arow) * 512) + kc8;
  }

#define STAGE(buf, k0)                                       \
  {                                                          \
    _Pragma("unroll")                                        \
    for (int s = 0; s < 4; ++s)                              \
      gload_lds16(gsrc[s] + (k0), &lds[buf][w * 4 + s][0]);  \
  }

  float bv[4];
#pragma unroll
  for (int j = 0; j < 4; ++j) bv[j] = bias[n0 + wn * 64 + j * 16 + arow];

  f32x4 acc[8][4] = {};
  STAGE(0, 0);
  STAGE(1, 32);
#pragma unroll
  for (int kt = 0; kt < 16; ++kt) {
    const int cur = kt & 1;
    if (kt < 15) WAIT_VM4(); else WAIT_VM0();   // oldest stage (tile kt) landed
    SBAR();
    bf16x8 af[8], bfr[4];
#pragma unroll
    for (int i = 0; i < 8; ++i)
      af[i] = *(const bf16x8*)&lds[cur][wm * 8 + i][lane * 8];
#pragma unroll
    for (int j = 0; j < 4; ++j)
      bfr[j] = *(const bf16x8*)&lds[cur][16 + wn * 4 + j][lane * 8];
    WAIT_LGKM0();                               // my reads of buf[cur] done
    __builtin_amdgcn_sched_barrier(0);
    SBAR();                                     // all reads done -> reuse ok
    if (kt < 14) STAGE(cur, (kt + 2) * 32);     // prefetch 2 ahead
#pragma unroll
    for (int i = 0; i < 8; ++i)
#pragma unroll
      for (int j = 0; j < 4; ++j)
        acc[i][j] = __builtin_amdgcn_mfma_f32_16x16x32_bf16(af[i], bfr[j], acc[i][j], 0, 0, 0);
  }
#undef STAGE

  const float sc = 0.17677669529663687f * 1.4426950408889634f;
  if (MODE == 0) {
    const int part = n0 >> 9;                    // 0:Q 1:K 2:V (uniform per block)
    short* dst = part == 0 ? qo : (part == 1 ? ko : vo);
    const float osc = part == 0 ? sc : 1.f;
    if (part == 2) {
      // V: (b,h,d,t) -> lane's 4 consecutive t = one 8B store
#pragma unroll
      for (int i = 0; i < 8; ++i) {
        const int mm0 = m0 + wm * 128 + i * 16 + g * 4;
        const int bb = mm0 >> 8, tt0 = mm0 & 255;
#pragma unroll
        for (int j = 0; j < 4; ++j) {
          const int c = n0 + wn * 64 + j * 16 + arow;
          const int d = c & 31, hh = (c >> 5) & 15;
          s16x4 qv;
#pragma unroll
          for (int r = 0; r < 4; ++r)
            qv[r] = f2bf(acc[i][j][r] + bv[j]);
          *(s16x4*)(dst + ((size_t)(bb * 16 + hh) * 32 + d) * 256 + tt0) = qv;
        }
      }
    } else {
      // Q,K: (b,h,t,d) scatter
#pragma unroll
      for (int i = 0; i < 8; ++i) {
        const int mm0 = m0 + wm * 128 + i * 16 + g * 4;
        const int bb = mm0 >> 8, tt0 = mm0 & 255;
#pragma unroll
        for (int j = 0; j < 4; ++j) {
          const int c = n0 + wn * 64 + j * 16 + arow;
          const int d = c & 31, hh = (c >> 5) & 15;
#pragma unroll
          for (int r = 0; r < 4; ++r)
            dst[((size_t)(bb * 16 + hh) * 256 + tt0 + r) * 32 + d] =
                f2bf((acc[i][j][r] + bv[j]) * osc);
        }
      }
    }
  } else {
#pragma unroll
    for (int i = 0; i < 8; ++i) {
      const int mm0 = m0 + wm * 128 + i * 16 + g * 4;
      const int bb = mm0 >> 8, tt0 = mm0 & 255;
#pragma unroll
      for (int j = 0; j < 4; ++j) {
        const int c = n0 + wn * 64 + j * 16 + arow;
#pragma unroll
        for (int r = 0; r < 4; ++r) {
          const int tt = tt0 + r;
          if (tt < 240) fo[(size_t)(bb * 240 + tt) * 512 + c] = acc[i][j][r] + bv[j];
        }
      }
    }
  }
}

// ---------------------------------------------------------------- attention
// One WG (8 waves, 512 thr) per (b,h); each wave owns 2 q-tiles. Swapped QK^T:
// lane holds S[q=lane&15][k=j*16+4g+r] -> softmax row fully lane-local; P
// packs directly into the A-fragment of mfma_f32_16x16x16_bf16 for PV.
// __launch_bounds__(512,4): VGPR cap 128 (NOT 8/EU=64 cap -> R7's spill bug);
// body fits ~64 VGPR -> up to 4 blocks/CU = 32 waves/CU.
__global__ __launch_bounds__(512, 4)
void k_attn(const short* __restrict__ Qg, const short* __restrict__ Kg,
            const short* __restrict__ Vg, const float* __restrict__ expB,
            short* __restrict__ O) {
  __shared__ alignas(16) short ldsK[15 * 512];      // frag-ordered K tiles
  __shared__ alignas(16) short ldsVT[32 * 264];     // V^T [d][t], stride 264
  const int lane = threadIdx.x & 63;
  const int w = threadIdx.x >> 6;                   // 0..7
  const int bh = blockIdx.x;
  const int h = bh & 15, b = bh >> 4;
  const short* Qb = Qg + (size_t)bh * 8192;
  const short* Kb = Kg + (size_t)bh * 8192;
  const short* Vb = Vg + (size_t)bh * 8192;
  const int arow = lane & 15;
  const int g = lane >> 4;

#pragma unroll
  for (int kt = 0; kt < 15; ++kt)
    if ((kt & 7) == w)
      gload_lds16(Kb + (kt * 16 + arow) * 32 + g * 8, &ldsK[kt * 512]);

  // V is (d,t): build padded V^T in LDS with wide copies
#pragma unroll
  for (int p = 0; p < 2; ++p) {
    int idx = p * 512 + threadIdx.x;   // 0..1023
    int d = idx >> 5, tc = idx & 31;
    *(bf16x8*)&ldsVT[d * 264 + tc * 8] = *(const bf16x8*)(Vb + d * 256 + tc * 8);
  }

  // Q is (b,h,t,d): direct fragment loads
  bf16x8 qf[2];
#pragma unroll
  for (int i = 0; i < 2; ++i)
    qf[i] = *(const bf16x8*)(Qb + ((w * 2 + i) * 16 + arow) * 32 + g * 8);
  __syncthreads();

  const f32x4 zf = {0.f, 0.f, 0.f, 0.f};
#pragma unroll
  for (int qt = 0; qt < 2; ++qt) {
    // ---- QK^T (swapped operands) ----
    f32x4 sacc[15];
#pragma unroll
    for (int j = 0; j < 15; ++j) {
      bf16x8 kf = *(const bf16x8*)&ldsK[j * 512 + lane * 8];
      sacc[j] = __builtin_amdgcn_mfma_f32_16x16x32_bf16(kf, qf[qt], zf, 0, 0, 0);
    }
    // ---- row max ----
    float m = fmaxf(fmaxf(sacc[0][0], sacc[0][1]), fmaxf(sacc[0][2], sacc[0][3]));
#pragma unroll
    for (int j = 1; j < 15; ++j)
      m = fmaxf(m, fmaxf(fmaxf(sacc[j][0], sacc[j][1]), fmaxf(sacc[j][2], sacc[j][3])));
    m = fmaxf(m, __shfl_xor(m, 16));
    m = fmaxf(m, __shfl_xor(m, 32));
    // ---- p = exp2(S - m) * exp(bias), pack to bf16 A-frags ----
    const float* ebp = expB + (size_t)((h * 16 + w * 2 + qt) * 15) * 256 + lane * 4;
    float sum = 0.f;
    s16x4 pa[15];
#pragma unroll
    for (int j = 0; j < 15; ++j) {
      float4 eb = *(const float4*)(ebp + j * 256);
      float p0 = __builtin_amdgcn_exp2f(sacc[j][0] - m) * eb.x;
      float p1 = __builtin_amdgcn_exp2f(sacc[j][1] - m) * eb.y;
      float p2 = __builtin_amdgcn_exp2f(sacc[j][2] - m) * eb.z;
      float p3 = __builtin_amdgcn_exp2f(sacc[j][3] - m) * eb.w;
      sum += (p0 + p1) + (p2 + p3);
      i32x2 pk;
      asm("v_cvt_pk_bf16_f32 %0, %1, %2" : "=v"(pk.x) : "v"(p0), "v"(p1));
      asm("v_cvt_pk_bf16_f32 %0, %1, %2" : "=v"(pk.y) : "v"(p2), "v"(p3));
      pa[j] = __builtin_bit_cast(s16x4, pk);
    }
    sum += __shfl_xor(sum, 16);
    sum += __shfl_xor(sum, 32);
    float rs = __builtin_amdgcn_rcpf(sum);
    float rsr[4];
#pragma unroll
    for (int r = 0; r < 4; ++r)
      rsr[r] = __shfl(rs, (lane & 48) + ((lane & 48) >> 2) + r, 64);
    // ---- PV: P A-frags x V^T B-frags, K=16 ----
    f32x4 oacc[2] = {};
#pragma unroll
    for (int j = 0; j < 15; ++j) {
#pragma unroll
      for (int dt = 0; dt < 2; ++dt) {
        s16x4 vt = *(const s16x4*)&ldsVT[(dt * 16 + arow) * 264 + j * 16 + g * 4];
        oacc[dt] = mfma16(pa[j], vt, oacc[dt]);
      }
    }
    const int q0 = (w * 2 + qt) * 16;
#pragma unroll
    for (int dt = 0; dt < 2; ++dt)
#pragma unroll
      for (int r = 0; r < 4; ++r)
        O[(size_t)(b * 256 + q0 + 4 * g + r) * 512 + h * 32 + dt * 16 + arow] =
            f2bf(oacc[dt][r] * rsr[r]);
  }
}

// ---------------------------------------------------------------- launch

extern "C" void kernel_launch(void* const* d_in, const int* in_sizes, int n_in,
                              void* d_out, int out_size, void* d_ws, size_t ws_size,
                              hipStream_t stream) {
  const float* x      = (const float*)d_in[0];
  const float* qkv_w  = (const float*)d_in[1];
  const float* qkv_b  = (const float*)d_in[2];
  const float* proj_w = (const float*)d_in[3];
  const float* proj_b = (const float*)d_in[4];
  const float* table  = (const float*)d_in[5];
  float* out = (float*)d_out;

  char* ws = (char*)d_ws;
  short* xb      = (short*)(ws);                 // 33,554,432 B (reused as attn_out)
  short* Qg      = (short*)(ws + 33554432u);     // 33,554,432 B  (b,h,t,d)
  short* Kg      = (short*)(ws + 67108864u);     // 33,554,432 B  (b,h,t,d)
  short* Vg      = (short*)(ws + 100663296u);    // 33,554,432 B  (b,h,d,t)
  float* expBf   = (float*)(ws + 134217728u);    //  3,932,160 B
  short* qkv_wt  = (short*)(ws + 138412032u);    //  1,572,864 B
  short* proj_wt = (short*)(ws + 139984896u);    //    524,288 B

  k_convert_x<<<16384, 256, 0, stream>>>(x, xb);
  k_transpose_w<<<(1536 * 512) / 256, 256, 0, stream>>>(qkv_w, qkv_wt, 512, 1536);
  k_transpose_w<<<(512 * 512) / 256, 256, 0, stream>>>(proj_w, proj_wt, 512, 512);
  k_biasfrag<<<960, 256, 0, stream>>>(table, expBf);
  k_gemm<0, 6><<<768, 512, 0, stream>>>(xb, qkv_wt, qkv_b, Qg, Kg, Vg, nullptr);
  k_attn<<<2048, 512, 0, stream>>>(Qg, Kg, Vg, expBf, xb);
  k_gemm<1, 2><<<256, 512, 0, stream>>>(xb, proj_wt, proj_b, nullptr, nullptr, nullptr, out);
}

// Round 9
// 204.683 us; speedup vs baseline: 2.6095x; 1.0217x over previous
//
#include <hip/hip_runtime.h>
#include <hip/hip_bf16.h>

typedef __attribute__((ext_vector_type(8))) short bf16x8;
typedef __attribute__((ext_vector_type(4))) short s16x4;
typedef __attribute__((ext_vector_type(2))) int i32x2;
typedef __attribute__((ext_vector_type(4))) float f32x4;

#define SC (0.17677669529663687f * 1.4426950408889634f)  // hd^-0.5 * log2(e)

__device__ __forceinline__ short f2bf(float f) {
  unsigned u = __builtin_bit_cast(unsigned, f);
  u = (u + 0x7FFFu + ((u >> 16) & 1u)) >> 16;
  return (short)u;
}

__device__ __forceinline__ void gload_lds16(const void* g, void* l) {
  __builtin_amdgcn_global_load_lds(
      (const __attribute__((address_space(1))) void*)g,
      (__attribute__((address_space(3))) void*)l, 16, 0, 0);
}

__device__ __forceinline__ f32x4 mfma16(s16x4 a, s16x4 b, f32x4 c) {
#if __has_builtin(__builtin_amdgcn_mfma_f32_16x16x16bf16_1k)
  return __builtin_amdgcn_mfma_f32_16x16x16bf16_1k(a, b, c, 0, 0, 0);
#else
  asm("v_mfma_f32_16x16x16_bf16 %0, %1, %2, %0" : "+v"(c) : "v"(a), "v"(b));
  return c;
#endif
}

#define SBAR()       asm volatile("s_barrier" ::: "memory")
#define WAIT_VM4()   asm volatile("s_waitcnt vmcnt(4)" ::: "memory")
#define WAIT_VM3()   asm volatile("s_waitcnt vmcnt(3)" ::: "memory")
#define WAIT_VM2()   asm volatile("s_waitcnt vmcnt(2)" ::: "memory")
#define WAIT_VM0()   asm volatile("s_waitcnt vmcnt(0)" ::: "memory")
#define WAIT_LGKM0() asm volatile("s_waitcnt lgkmcnt(0)" ::: "memory")

// ---------------------------------------------------------------- prep kernels

// x (B,240,512) fp32 -> xb (B*256,512) bf16, zero-padded rows 240..255
__global__ void k_convert_x(const float* __restrict__ x, short* __restrict__ xb) {
  int i = blockIdx.x * 256 + threadIdx.x;
  int c4 = i & 127;
  int row = i >> 7;
  int b = row >> 8, t = row & 255;
  s16x4 o = {0, 0, 0, 0};
  if (t < 240) {
    const float4 v = *(const float4*)(x + (size_t)(b * 240 + t) * 512 + c4 * 4);
    o.x = f2bf(v.x); o.y = f2bf(v.y); o.z = f2bf(v.z); o.w = f2bf(v.w);
  }
  *(s16x4*)(xb + (size_t)row * 512 + c4 * 4) = o;
}

// W (K,N) fp32 -> Wt (N,K) bf16; first nScaled output cols scaled by SC
__global__ void k_transpose_w(const float* __restrict__ W, short* __restrict__ Wt,
                              int K, int N, int nScaled) {
  int i = blockIdx.x * 256 + threadIdx.x;      // n*K + k
  if (i >= K * N) return;
  int k = i % K, n = i / K;
  float v = W[(size_t)k * N + n];
  if (n < nScaled) v *= SC;
  Wt[i] = f2bf(v);
}

// rel_bias_table (961,16) -> expB in swapped-QK fragment layout
__global__ void k_biasfrag(const float* __restrict__ table, float* __restrict__ expB) {
  int i = blockIdx.x * 256 + threadIdx.x;
  int lane = i & 63;
  int rest = i >> 6;
  int j = rest % 15;
  int hq = rest / 15;
  int q = (hq & 15) * 16 + (lane & 15);
  int h = hq >> 4;
  int kbase = j * 16 + ((lane >> 4) << 2);
  float4 o;
  float* op = &o.x;
#pragma unroll
  for (int r = 0; r < 4; ++r) {
    int k = kbase + r;
    int idx = ((q >> 4) - (k >> 4) + 15) * 31 + ((q & 15) - (k & 15) + 15);
    op[r] = __builtin_amdgcn_exp2f(table[idx * 16 + h] * 1.4426950408889634f);
  }
  *(float4*)(expB + (size_t)i * 4) = o;
}

// ---------------------------------------------------------------- fused QKV + attention
// One block per (b,h), 512 thr / 8 waves. Phase G: qkv = x(256x512) x W(512x96)
// via dbuf counted-vmcnt K-loop (wave: 32 tokens x 96 outs, 12 MFMA/step).
// Phase T: scatter acc through LDS into attn frag layouts (K frag-order,
// V^T stride-264, Q padded scratch). Phase A: R8's verified swapped-QK softmax
// + PV body. LDS = 52KB union(staging, attn) -> 2 blocks/CU.
__global__ __launch_bounds__(512, 2)
void k_fused(const short* __restrict__ xb, const short* __restrict__ wt,
             const float* __restrict__ qkvb, const float* __restrict__ expB,
             short* __restrict__ O) {
  __shared__ alignas(16) char smem[53248];
  short* sA  = (short*)smem;                 // staging: [2][16][512]  (32KB)
  short* sW  = (short*)(smem + 32768);       // staging: [2][6][512]   (12KB)
  short* sK  = (short*)smem;                 // overlay: 15 x 512      (15360B)
  short* sVT = (short*)(smem + 15360);       // overlay: 32 x 264      (16896B)
  short* sQ  = (short*)(smem + 32256);       // overlay: 8 x 32 x 40   (20480B)

  const int lane = threadIdx.x & 63;
  const int w = threadIdx.x >> 6;            // 0..7
  const int arow = lane & 15;
  const int g = lane >> 4;
  // bijective XCD swizzle: XCD x gets b = x*16..x*16+15 (all h) -> x-slab L2-hot
  const int bid = blockIdx.x;
  const int swz = (bid & 7) * 256 + (bid >> 3);
  const int b = swz >> 4, h = swz & 15;

  const short* Ab = xb + (size_t)b * 256 * 512;
  int wbase;
  if (w < 2)      wbase = h * 32 + w * 16;
  else if (w < 4) wbase = 512 + h * 32 + (w - 2) * 16;
  else            wbase = 1024 + h * 32 + (w - 4) * 16;
  const short* Asrc0 = Ab + (size_t)((2 * w) * 16 + arow) * 512 + g * 8;
  const short* Asrc1 = Ab + (size_t)((2 * w + 1) * 16 + arow) * 512 + g * 8;
  const short* Wsrc  = wt + (size_t)(wbase + arow) * 512 + g * 8;

#define FSTAGE(buf, kc)                                                  \
  {                                                                      \
    gload_lds16(Asrc0 + (kc) * 32, sA + (buf) * 8192 + (2 * w) * 512);   \
    gload_lds16(Asrc1 + (kc) * 32, sA + (buf) * 8192 + (2 * w + 1) * 512); \
    if (w < 6) gload_lds16(Wsrc + (kc) * 32, sW + (buf) * 3072 + w * 512); \
  }

  f32x4 acc[2][6] = {};
  FSTAGE(0, 0);
  FSTAGE(1, 1);
#pragma unroll
  for (int kc = 0; kc < 16; ++kc) {
    const int cur = kc & 1;
    if (kc == 15) { WAIT_VM0(); }
    else if (w < 6) { WAIT_VM3(); } else { WAIT_VM2(); }
    SBAR();
    bf16x8 af[2], wf[6];
    af[0] = *(const bf16x8*)(sA + cur * 8192 + (2 * w) * 512 + lane * 8);
    af[1] = *(const bf16x8*)(sA + cur * 8192 + (2 * w + 1) * 512 + lane * 8);
#pragma unroll
    for (int n = 0; n < 6; ++n)
      wf[n] = *(const bf16x8*)(sW + cur * 3072 + n * 512 + lane * 8);
    WAIT_LGKM0();
    __builtin_amdgcn_sched_barrier(0);
    SBAR();
    if (kc < 14) FSTAGE(cur, kc + 2);
#pragma unroll
    for (int i = 0; i < 2; ++i)
#pragma unroll
      for (int n = 0; n < 6; ++n)
        acc[i][n] = __builtin_amdgcn_mfma_f32_16x16x32_bf16(af[i], wf[n], acc[i][n], 0, 0, 0);
  }
#undef FSTAGE
  __syncthreads();   // gemm reads done everywhere -> safe to overlay staging LDS

  // ---- Phase T: acc -> LDS in attn fragment layouts (+bias; q pre-scaled) ----
  const float qb0 = qkvb[h * 32 + arow] * SC;
  const float qb1 = qkvb[h * 32 + 16 + arow] * SC;
  const float kb0 = qkvb[512 + h * 32 + arow];
  const float kb1 = qkvb[512 + h * 32 + 16 + arow];
  const float vb0 = qkvb[1024 + h * 32 + arow];
  const float vb1 = qkvb[1024 + h * 32 + 16 + arow];
#pragma unroll
  for (int i = 0; i < 2; ++i) {
#pragma unroll
    for (int r = 0; r < 4; ++r) {
      const int tok = w * 32 + i * 16 + 4 * g + r;   // 0..255
      const int j = tok >> 4, t = tok & 15;
      if (j < 15) {  // K tile 15 (tokens 240+) never read
        const int d0 = arow, d1 = 16 + arow;
        sK[j * 512 + (t + ((d0 >> 3) << 4)) * 8 + (d0 & 7)] = f2bf(acc[i][2][r] + kb0);
        sK[j * 512 + (t + ((d1 >> 3) << 4)) * 8 + (d1 & 7)] = f2bf(acc[i][3][r] + kb1);
      }
      sVT[arow * 264 + tok]        = f2bf(acc[i][4][r] + vb0);
      sVT[(16 + arow) * 264 + tok] = f2bf(acc[i][5][r] + vb1);
      const int tl = i * 16 + 4 * g + r;             // 0..31 within wave
      sQ[w * 1280 + tl * 40 + arow]      = f2bf(acc[i][0][r] + qb0);
      sQ[w * 1280 + tl * 40 + 16 + arow] = f2bf(acc[i][1][r] + qb1);
    }
  }
  __syncthreads();

  // ---- Phase A: swapped-QK softmax + PV (R8 attn body) ----
  bf16x8 qf[2];
  qf[0] = *(const bf16x8*)(sQ + w * 1280 + arow * 40 + g * 8);
  qf[1] = *(const bf16x8*)(sQ + w * 1280 + (16 + arow) * 40 + g * 8);

  const f32x4 zf = {0.f, 0.f, 0.f, 0.f};
#pragma unroll
  for (int qt = 0; qt < 2; ++qt) {
    f32x4 sacc[15];
#pragma unroll
    for (int j = 0; j < 15; ++j) {
      bf16x8 kf = *(const bf16x8*)(sK + j * 512 + lane * 8);
      sacc[j] = __builtin_amdgcn_mfma_f32_16x16x32_bf16(kf, qf[qt], zf, 0, 0, 0);
    }
    float m = fmaxf(fmaxf(sacc[0][0], sacc[0][1]), fmaxf(sacc[0][2], sacc[0][3]));
#pragma unroll
    for (int j = 1; j < 15; ++j)
      m = fmaxf(m, fmaxf(fmaxf(sacc[j][0], sacc[j][1]), fmaxf(sacc[j][2], sacc[j][3])));
    m = fmaxf(m, __shfl_xor(m, 16));
    m = fmaxf(m, __shfl_xor(m, 32));
    const float* ebp = expB + (size_t)((h * 16 + w * 2 + qt) * 15) * 256 + lane * 4;
    float sum = 0.f;
    s16x4 pa[15];
#pragma unroll
    for (int j = 0; j < 15; ++j) {
      float4 eb = *(const float4*)(ebp + j * 256);
      float p0 = __builtin_amdgcn_exp2f(sacc[j][0] - m) * eb.x;
      float p1 = __builtin_amdgcn_exp2f(sacc[j][1] - m) * eb.y;
      float p2 = __builtin_amdgcn_exp2f(sacc[j][2] - m) * eb.z;
      float p3 = __builtin_amdgcn_exp2f(sacc[j][3] - m) * eb.w;
      sum += (p0 + p1) + (p2 + p3);
      i32x2 pk;
      asm("v_cvt_pk_bf16_f32 %0, %1, %2" : "=v"(pk.x) : "v"(p0), "v"(p1));
      asm("v_cvt_pk_bf16_f32 %0, %1, %2" : "=v"(pk.y) : "v"(p2), "v"(p3));
      pa[j] = __builtin_bit_cast(s16x4, pk);
    }
    sum += __shfl_xor(sum, 16);
    sum += __shfl_xor(sum, 32);
    float rs = __builtin_amdgcn_rcpf(sum);
    float rsr[4];
#pragma unroll
    for (int r = 0; r < 4; ++r)
      rsr[r] = __shfl(rs, (lane & 48) + ((lane & 48) >> 2) + r, 64);
    f32x4 oacc[2] = {};
#pragma unroll
    for (int j = 0; j < 15; ++j) {
#pragma unroll
      for (int dt = 0; dt < 2; ++dt) {
        s16x4 vt = *(const s16x4*)(sVT + (dt * 16 + arow) * 264 + j * 16 + g * 4);
        oacc[dt] = mfma16(pa[j], vt, oacc[dt]);
      }
    }
    const int q0 = (w * 2 + qt) * 16;
#pragma unroll
    for (int dt = 0; dt < 2; ++dt)
#pragma unroll
      for (int r = 0; r < 4; ++r)
        O[(size_t)(b * 256 + q0 + 4 * g + r) * 512 + h * 32 + dt * 16 + arow] =
            f2bf(oacc[dt][r] * rsr[r]);
  }
}

// ---------------------------------------------------------------- proj GEMM (R8, MODE 1)
template <int MODE, int NBN>
__global__ __launch_bounds__(512, 2)
void k_gemm(const short* __restrict__ A, const short* __restrict__ Bt,
            const float* __restrict__ bias,
            short* __restrict__ qo, short* __restrict__ ko, short* __restrict__ vo,
            float* __restrict__ fo) {
  __shared__ alignas(16) short lds[2][32][512];
  const int lane = threadIdx.x & 63;
  const int w = threadIdx.x >> 6;
  const int wm = w >> 2;
  const int wn = w & 3;
  const int arow = lane & 15;
  const int g = lane >> 4;
  const int kc8 = g * 8;

  const int nwg = 128 * NBN;
  const int bid = blockIdx.x;
  const int swz = (bid & 7) * (nwg >> 3) + (bid >> 3);
  const int nb = swz % NBN, mc = swz / NBN;
  const int n0 = nb * 256, m0 = mc * 256;

  const short* gsrc[4];
#pragma unroll
  for (int s = 0; s < 4; ++s) {
    const int t = w * 4 + s;
    gsrc[s] = (t < 16 ? A + (size_t)(m0 + t * 16 + arow) * 512
                      : Bt + (size_t)(n0 + (t - 16) * 16 + arow) * 512) + kc8;
  }

#define STAGE(buf, k0)                                       \
  {                                                          \
    _Pragma("unroll")                                        \
    for (int s = 0; s < 4; ++s)                              \
      gload_lds16(gsrc[s] + (k0), &lds[buf][w * 4 + s][0]);  \
  }

  float bv[4];
#pragma unroll
  for (int j = 0; j < 4; ++j) bv[j] = bias[n0 + wn * 64 + j * 16 + arow];

  f32x4 acc[8][4] = {};
  STAGE(0, 0);
  STAGE(1, 32);
#pragma unroll
  for (int kt = 0; kt < 16; ++kt) {
    const int cur = kt & 1;
    if (kt < 15) WAIT_VM4(); else WAIT_VM0();
    SBAR();
    bf16x8 af[8], bfr[4];
#pragma unroll
    for (int i = 0; i < 8; ++i)
      af[i] = *(const bf16x8*)&lds[cur][wm * 8 + i][lane * 8];
#pragma unroll
    for (int j = 0; j < 4; ++j)
      bfr[j] = *(const bf16x8*)&lds[cur][16 + wn * 4 + j][lane * 8];
    WAIT_LGKM0();
    __builtin_amdgcn_sched_barrier(0);
    SBAR();
    if (kt < 14) STAGE(cur, (kt + 2) * 32);
#pragma unroll
    for (int i = 0; i < 8; ++i)
#pragma unroll
      for (int j = 0; j < 4; ++j)
        acc[i][j] = __builtin_amdgcn_mfma_f32_16x16x32_bf16(af[i], bfr[j], acc[i][j], 0, 0, 0);
  }
#undef STAGE

#pragma unroll
  for (int i = 0; i < 8; ++i) {
    const int mm0 = m0 + wm * 128 + i * 16 + g * 4;
    const int bb = mm0 >> 8, tt0 = mm0 & 255;
#pragma unroll
    for (int j = 0; j < 4; ++j) {
      const int c = n0 + wn * 64 + j * 16 + arow;
#pragma unroll
      for (int r = 0; r < 4; ++r) {
        const int tt = tt0 + r;
        if (tt < 240) fo[(size_t)(bb * 240 + tt) * 512 + c] = acc[i][j][r] + bv[j];
      }
    }
  }
}

// ---------------------------------------------------------------- launch

extern "C" void kernel_launch(void* const* d_in, const int* in_sizes, int n_in,
                              void* d_out, int out_size, void* d_ws, size_t ws_size,
                              hipStream_t stream) {
  const float* x      = (const float*)d_in[0];
  const float* qkv_w  = (const float*)d_in[1];
  const float* qkv_b  = (const float*)d_in[2];
  const float* proj_w = (const float*)d_in[3];
  const float* proj_b = (const float*)d_in[4];
  const float* table  = (const float*)d_in[5];
  float* out = (float*)d_out;

  char* ws = (char*)d_ws;
  short* xb      = (short*)(ws);                 // 33,554,432 B  x bf16 padded
  short* ao      = (short*)(ws + 33554432u);     // 33,554,432 B  attn out (b*256+t, 512)
  float* expBf   = (float*)(ws + 134217728u);    //  3,932,160 B
  short* qkv_wt  = (short*)(ws + 138412032u);    //  1,572,864 B  (n-major, q cols pre-scaled)
  short* proj_wt = (short*)(ws + 139984896u);    //    524,288 B

  k_convert_x<<<16384, 256, 0, stream>>>(x, xb);
  k_transpose_w<<<(1536 * 512) / 256, 256, 0, stream>>>(qkv_w, qkv_wt, 512, 1536, 512);
  k_transpose_w<<<(512 * 512) / 256, 256, 0, stream>>>(proj_w, proj_wt, 512, 512, 0);
  k_biasfrag<<<960, 256, 0, stream>>>(table, expBf);
  k_fused<<<2048, 512, 0, stream>>>(xb, qkv_wt, qkv_b, expBf, ao);
  k_gemm<1, 2><<<256, 512, 0, stream>>>(ao, proj_wt, proj_b, nullptr, nullptr, nullptr, out);
}